// Round 1
// 171.837 us; speedup vs baseline: 2.2508x; 2.2508x over previous
//
#include <hip/hip_runtime.h>

#define N_ATOMS 50000
#define KMAX 32
#define EMB_ATOM 256
#define EP_IN 64
#define EP_OUT 64
#define EMB_RBF 16
#define NEDGES (N_ATOMS * KMAX)

typedef _Float16 half_t;
typedef __attribute__((ext_vector_type(4))) _Float16 half4_t;
typedef __attribute__((ext_vector_type(8))) _Float16 half8_t;
typedef __attribute__((ext_vector_type(4))) float f32x4;

static_assert(N_ATOMS % 16 == 0, "fused kernel assumes 16 atoms per block");
static_assert(sizeof(half4_t) == 8 && sizeof(half8_t) == 16, "vector sizes");

// ---------------------------------------------------------------------------
// Kernel A: x_b = h @ W_down  (50000x256)@(256x64) -> (50000x64), stored f16.
// fp32 compute (1.6 GFLOP, ~8 us), f16 store halves downstream gather bytes.
// ---------------------------------------------------------------------------
__global__ __launch_bounds__(256) void xb_gemm(const float* __restrict__ h,
                                               const float* __restrict__ Wd,
                                               half_t* __restrict__ xbh) {
    __shared__ float As[16 * 68];  // [k][m], stride 68
    __shared__ float Bs[16 * 64];  // [k][n]
    const int t = threadIdx.x;
    const int r0 = blockIdx.x * 64;
    const int tr = t >> 4;
    const int tc = t & 15;
    float acc[4][4] = {};

    for (int k0 = 0; k0 < 256; k0 += 16) {
        {
            int m = t >> 2, kk0 = (t & 3) << 2;
            int row = r0 + m;
            float4 v = make_float4(0.f, 0.f, 0.f, 0.f);
            if (row < N_ATOMS)
                v = *reinterpret_cast<const float4*>(&h[(size_t)row * 256 + k0 + kk0]);
            As[(kk0 + 0) * 68 + m] = v.x;
            As[(kk0 + 1) * 68 + m] = v.y;
            As[(kk0 + 2) * 68 + m] = v.z;
            As[(kk0 + 3) * 68 + m] = v.w;
        }
        {
            int kk = t >> 4, n0 = (t & 15) << 2;
            *reinterpret_cast<float4*>(&Bs[kk * 64 + n0]) =
                *reinterpret_cast<const float4*>(&Wd[(k0 + kk) * 64 + n0]);
        }
        __syncthreads();
        #pragma unroll
        for (int kk = 0; kk < 16; ++kk) {
            float4 av = *reinterpret_cast<const float4*>(&As[kk * 68 + tr * 4]);
            float4 bv = *reinterpret_cast<const float4*>(&Bs[kk * 64 + tc * 4]);
            float aa[4] = {av.x, av.y, av.z, av.w};
            float bb[4] = {bv.x, bv.y, bv.z, bv.w};
            #pragma unroll
            for (int i = 0; i < 4; ++i)
                #pragma unroll
                for (int j = 0; j < 4; ++j) acc[i][j] += aa[i] * bb[j];
        }
        __syncthreads();
    }
    #pragma unroll
    for (int i = 0; i < 4; ++i) {
        int row = r0 + tr * 4 + i;
        if (row < N_ATOMS) {
            half4_t hv;
            #pragma unroll
            for (int j = 0; j < 4; ++j) hv[j] = (half_t)acc[i][j];
            *reinterpret_cast<half4_t*>(&xbh[(size_t)row * 64 + tc * 4]) = hv;
        }
    }
}

// ---------------------------------------------------------------------------
// Kernels B/C: srcidx[atom][k] = source atom (-1 = zero row)
// ---------------------------------------------------------------------------
__global__ void init_sidx(int* __restrict__ sidx) {
    int i = blockIdx.x * 256 + threadIdx.x;
    if (i < NEDGES) sidx[i] = -1;
}

__global__ void scatter_sidx(const int* __restrict__ ei, const int* __restrict__ tni,
                             int* __restrict__ sidx) {
    int i = blockIdx.x * 256 + threadIdx.x;
    if (i < NEDGES) {
        int s = ei[i];
        int d = ei[NEDGES + i];
        int k = tni[i];
        sidx[d * KMAX + k] = s;
    }
}

// ---------------------------------------------------------------------------
// Prep: WbP[o][idx] = f16(Wb[rp(idx)][o]) where idx is the rp-permutation the
// fused kernel's phase-1 D-fragments write:
//   idx = pc*256 + g*64 + c*4 + i  <->  r = g*4+i, p = pc*16+c, rp = r*64+p
// ---------------------------------------------------------------------------
__global__ void prep_wb(const float* __restrict__ Wb, half_t* __restrict__ WbP) {
    int i = blockIdx.x * 256 + threadIdx.x;  // 65536 = 64 o * 1024 idx
    int o = i >> 10, idx = i & 1023;
    int r = ((idx >> 6) & 3) * 4 + (idx & 3);
    int p = (idx >> 8) * 16 + ((idx >> 2) & 15);
    WbP[i] = (half_t)Wb[(size_t)(r * 64 + p) * 64 + o];
}

// WuP[oc][o] = f16(Wu[o][oc])  (256 x 64)
__global__ void prep_wu(const float* __restrict__ Wu, half_t* __restrict__ WuP) {
    int i = blockIdx.x * 256 + threadIdx.x;  // 16384
    int oc = i >> 6, o = i & 63;
    WuP[i] = (half_t)Wu[(size_t)o * 256 + oc];
}

// ---------------------------------------------------------------------------
// Fused steps 3-5, MFMA f16. 16 atoms / block, 4 waves, 256 threads.
//
// MFMA layouts used (16x16 family, gfx950):
//   A-frag:  row m = lane&15,  k = (lane>>4)*W + j   (W=4 for x16, 8 for x32)
//   B-frag:  col n = lane&15,  k = (lane>>4)*W + j
//   C/D:     col n = lane&15,  row m = (lane>>4)*4 + i
//
// Phase 1 transpose trick: load gathered x2 16x16 chunk in A-layout
// (k-rows of x2 as MFMA rows, p as MFMA k -> contiguous 8B global loads),
// multiply by identity: D-frag of the result IS the B-frag of the chunk
// with (k,p) in the roles MFMA needs. No LDS staging of x2 at all.
// ---------------------------------------------------------------------------
__global__ __launch_bounds__(256) void fused(const half_t* __restrict__ xbh,
                                             const float*  __restrict__ rad,   // (N,16,32) f32
                                             const int*    __restrict__ sidxg, // (N,32)
                                             const half_t* __restrict__ WbP,   // (64,1024) permuted
                                             const half_t* __restrict__ WuP,   // (256,64) transposed
                                             float* __restrict__ out) {        // (N,256)
    __shared__ __align__(16) half_t xba2s[16 * 1024];  // 32 KB, rows XOR-swizzled
    __shared__ __align__(16) half_t houts[16 * 64];    //  2 KB, rows XOR-swizzled
    __shared__ int sidx_s[16 * KMAX];                  //  2 KB

    const int t = threadIdx.x;
    const int w = t >> 6;        // wave 0..3
    const int l = t & 63;
    const int c = l & 15;        // lane col within 16-group
    const int g = l >> 4;        // 16-lane group 0..3
    const int a0 = blockIdx.x * 16;

    sidx_s[t]       = sidxg[(size_t)a0 * KMAX + t];
    sidx_s[t + 256] = sidxg[(size_t)a0 * KMAX + t + 256];
    __syncthreads();

    const f32x4 fzero = {0.f, 0.f, 0.f, 0.f};

    // identity B-frag for the transpose mfma: B[k][n] = (k==n)
    half4_t ident;
    #pragma unroll
    for (int j = 0; j < 4; ++j) ident[j] = (half_t)((g * 4 + j == c) ? 1.0f : 0.0f);

    // ---------------- phase 1: xba2 = rad @ x2 (per atom), 4 atoms per wave --
    for (int as = 0; as < 4; ++as) {
        const int a = w * 4 + as;  // local atom 0..15
        const float* radp = &rad[(size_t)(a0 + a) * 512];

        // rad A-frags, two K-halves of 16: A[m=r][k] = rad[r=c][kc*16 + g*4+j]
        half4_t radF[2];
        #pragma unroll
        for (int kc = 0; kc < 2; ++kc) {
            f32x4 rv = *reinterpret_cast<const f32x4*>(radp + c * 32 + kc * 16 + g * 4);
            #pragma unroll
            for (int j = 0; j < 4; ++j) radF[kc][j] = (half_t)rv[j];
        }

        f32x4 acc[4] = {fzero, fzero, fzero, fzero};  // 4 p-chunks of 16
        #pragma unroll
        for (int kc = 0; kc < 2; ++kc) {
            int s = sidx_s[a * KMAX + kc * 16 + c];   // source row for x2 k-row (kc*16+c)
            const half_t* srow = &xbh[(size_t)(s < 0 ? 0 : s) * 64];
            #pragma unroll
            for (int pc = 0; pc < 4; ++pc) {
                // gather chunk in A-layout: A[m=c][k=g*4+j] = x2[kc*16+c][pc*16+g*4+j]
                half4_t gf = {(half_t)0, (half_t)0, (half_t)0, (half_t)0};
                if (s >= 0)
                    gf = *reinterpret_cast<const half4_t*>(srow + pc * 16 + g * 4);
                // transpose via identity mfma (exact)
                f32x4 tD = __builtin_amdgcn_mfma_f32_16x16x16f16(gf, ident, fzero, 0, 0, 0);
                half4_t b2;
                #pragma unroll
                for (int j = 0; j < 4; ++j) b2[j] = (half_t)tD[j];
                // accumulate: C1[r][p] += rad * x2
                acc[pc] = __builtin_amdgcn_mfma_f32_16x16x16f16(radF[kc], b2, acc[pc], 0, 0, 0);
            }
        }
        // write D-frags to xba2s in permuted order: lane holds (r=g*4+i, p=pc*16+c)
        // idx = pc*256 + g*64 + c*4 + i ; byte = a*2048 + idx*2, row-swizzled
        #pragma unroll
        for (int pc = 0; pc < 4; ++pc) {
            half4_t hv;
            #pragma unroll
            for (int j = 0; j < 4; ++j) hv[j] = (half_t)acc[pc][j];
            int byte = (a * 2048 + pc * 512 + g * 128 + c * 8) ^ ((a & 7) << 4);
            *reinterpret_cast<half4_t*>(reinterpret_cast<char*>(xba2s) + byte) = hv;
        }
    }
    __syncthreads();

    // ---------------- phase 2: h_out(16x64) = xba2(16x1024) @ WbP^T ----------
    // wave w owns o-tile w (o = w*16 + c); M = 16 atoms; K = 1024, x32 mfma.
    f32x4 acc2 = fzero;
    {
        const half_t* wbrow = &WbP[(size_t)(w * 16 + c) * 1024];
        #pragma unroll 8
        for (int K0 = 0; K0 < 1024; K0 += 32) {
            int abyte = (c * 2048 + K0 * 2 + g * 16) ^ ((c & 7) << 4);  // atom row = c
            half8_t af = *reinterpret_cast<const half8_t*>(
                reinterpret_cast<const char*>(xba2s) + abyte);
            half8_t bf = *reinterpret_cast<const half8_t*>(wbrow + K0 + g * 8);
            acc2 = __builtin_amdgcn_mfma_f32_16x16x32_f16(af, bf, acc2, 0, 0, 0);
        }
    }
    // hout[m=g*4+i][o=w*16+c], row-swizzled
    #pragma unroll
    for (int i = 0; i < 4; ++i) {
        int m = g * 4 + i;
        int byte = (m * 128 + (w * 16 + c) * 2) ^ ((m & 7) << 4);
        *reinterpret_cast<half_t*>(reinterpret_cast<char*>(houts) + byte) = (half_t)acc2[i];
    }
    __syncthreads();

    // ---------------- phase 3: out(16x256) = hout(16x64) @ WuP^T -------------
    // wave w owns oc in [w*64, w*64+64); A row m = atom = c; K = 64.
    half8_t ha[2];
    #pragma unroll
    for (int kk = 0; kk < 2; ++kk) {
        int byte = (c * 128 + kk * 64 + g * 16) ^ ((c & 7) << 4);
        ha[kk] = *reinterpret_cast<const half8_t*>(
            reinterpret_cast<const char*>(houts) + byte);
    }
    #pragma unroll
    for (int nt = 0; nt < 4; ++nt) {
        int oc0 = w * 64 + nt * 16;
        f32x4 acc3 = fzero;
        #pragma unroll
        for (int kk = 0; kk < 2; ++kk) {
            half8_t bf = *reinterpret_cast<const half8_t*>(
                &WuP[(size_t)(oc0 + c) * 64 + kk * 32 + g * 8]);
            acc3 = __builtin_amdgcn_mfma_f32_16x16x32_f16(ha[kk], bf, acc3, 0, 0, 0);
        }
        #pragma unroll
        for (int i = 0; i < 4; ++i)
            out[(size_t)(a0 + g * 4 + i) * 256 + oc0 + c] = acc3[i];
    }
}

// ---------------------------------------------------------------------------
extern "C" void kernel_launch(void* const* d_in, const int* in_sizes, int n_in,
                              void* d_out, int out_size, void* d_ws, size_t ws_size,
                              hipStream_t stream) {
    const float* h   = (const float*)d_in[0];
    const float* rad = (const float*)d_in[1];
    const int*   ei  = (const int*)d_in[2];
    const int*   tni = (const int*)d_in[3];
    const float* Wd  = (const float*)d_in[4];
    const float* Wb  = (const float*)d_in[5];
    const float* Wu  = (const float*)d_in[6];
    float* out = (float*)d_out;

    // workspace: xbh f16 (6.4MB) | sidx i32 (6.4MB) | WbP f16 (128KB) | WuP f16 (32KB)
    half_t* xbh  = (half_t*)d_ws;
    int*    sidx = (int*)((char*)d_ws + (size_t)N_ATOMS * EP_IN * sizeof(half_t));
    half_t* WbP  = (half_t*)((char*)sidx + (size_t)NEDGES * sizeof(int));
    half_t* WuP  = WbP + 64 * 1024;

    xb_gemm<<<(N_ATOMS + 63) / 64, 256, 0, stream>>>(h, Wd, xbh);
    init_sidx<<<(NEDGES + 255) / 256, 256, 0, stream>>>(sidx);
    scatter_sidx<<<(NEDGES + 255) / 256, 256, 0, stream>>>(ei, tni, sidx);
    prep_wb<<<256, 256, 0, stream>>>(Wb, WbP);
    prep_wu<<<64, 256, 0, stream>>>(Wu, WuP);
    fused<<<N_ATOMS / 16, 256, 0, stream>>>(xbh, rad, sidx, WbP, WuP, out);
}

// Round 2
// 168.874 us; speedup vs baseline: 2.2903x; 1.0175x over previous
//
#include <hip/hip_runtime.h>

#define N_ATOMS 50000
#define KMAX 32
#define EMB_ATOM 256
#define EP_IN 64
#define EP_OUT 64
#define EMB_RBF 16
#define NEDGES (N_ATOMS * KMAX)

typedef _Float16 half_t;
typedef __attribute__((ext_vector_type(2))) _Float16 half2_t;
typedef __attribute__((ext_vector_type(4))) _Float16 half4_t;
typedef __attribute__((ext_vector_type(8))) _Float16 half8_t;
typedef __attribute__((ext_vector_type(4))) float f32x4;

static_assert(N_ATOMS % 16 == 0, "fused kernel assumes 16 atoms per block");
static_assert(sizeof(half4_t) == 8 && sizeof(half8_t) == 16, "vector sizes");

// ---------------------------------------------------------------------------
// Kernel A: x_b = h @ W_down  (50000x256)@(256x64) -> (50000x64), stored f16.
// ---------------------------------------------------------------------------
__global__ __launch_bounds__(256) void xb_gemm(const float* __restrict__ h,
                                               const float* __restrict__ Wd,
                                               half_t* __restrict__ xbh) {
    __shared__ float As[16 * 68];  // [k][m], stride 68
    __shared__ float Bs[16 * 64];  // [k][n]
    const int t = threadIdx.x;
    const int r0 = blockIdx.x * 64;
    const int tr = t >> 4;
    const int tc = t & 15;
    float acc[4][4] = {};

    for (int k0 = 0; k0 < 256; k0 += 16) {
        {
            int m = t >> 2, kk0 = (t & 3) << 2;
            int row = r0 + m;
            float4 v = make_float4(0.f, 0.f, 0.f, 0.f);
            if (row < N_ATOMS)
                v = *reinterpret_cast<const float4*>(&h[(size_t)row * 256 + k0 + kk0]);
            As[(kk0 + 0) * 68 + m] = v.x;
            As[(kk0 + 1) * 68 + m] = v.y;
            As[(kk0 + 2) * 68 + m] = v.z;
            As[(kk0 + 3) * 68 + m] = v.w;
        }
        {
            int kk = t >> 4, n0 = (t & 15) << 2;
            *reinterpret_cast<float4*>(&Bs[kk * 64 + n0]) =
                *reinterpret_cast<const float4*>(&Wd[(k0 + kk) * 64 + n0]);
        }
        __syncthreads();
        #pragma unroll
        for (int kk = 0; kk < 16; ++kk) {
            float4 av = *reinterpret_cast<const float4*>(&As[kk * 68 + tr * 4]);
            float4 bv = *reinterpret_cast<const float4*>(&Bs[kk * 64 + tc * 4]);
            float aa[4] = {av.x, av.y, av.z, av.w};
            float bb[4] = {bv.x, bv.y, bv.z, bv.w};
            #pragma unroll
            for (int i = 0; i < 4; ++i)
                #pragma unroll
                for (int j = 0; j < 4; ++j) acc[i][j] += aa[i] * bb[j];
        }
        __syncthreads();
    }
    #pragma unroll
    for (int i = 0; i < 4; ++i) {
        int row = r0 + tr * 4 + i;
        if (row < N_ATOMS) {
            half4_t hv;
            #pragma unroll
            for (int j = 0; j < 4; ++j) hv[j] = (half_t)acc[i][j];
            *reinterpret_cast<half4_t*>(&xbh[(size_t)row * 64 + tc * 4]) = hv;
        }
    }
}

// ---------------------------------------------------------------------------
// Kernels B/C: srcidx[atom][k] = source atom (-1 = zero row)
// ---------------------------------------------------------------------------
__global__ void init_sidx(int* __restrict__ sidx) {
    int i = blockIdx.x * 256 + threadIdx.x;
    if (i < NEDGES) sidx[i] = -1;
}

__global__ void scatter_sidx(const int* __restrict__ ei, const int* __restrict__ tni,
                             int* __restrict__ sidx) {
    int i = blockIdx.x * 256 + threadIdx.x;
    if (i < NEDGES) {
        int s = ei[i];
        int d = ei[NEDGES + i];
        int k = tni[i];
        sidx[d * KMAX + k] = s;
    }
}

// ---------------------------------------------------------------------------
// Prep: WbP[o][idx] = f16(Wb[rp(idx)][o]),
//   idx = pc*256 + g*64 + c*4 + i  <->  r = g*4+i, p = pc*16+c
// ---------------------------------------------------------------------------
__global__ void prep_wb(const float* __restrict__ Wb, half_t* __restrict__ WbP) {
    int i = blockIdx.x * 256 + threadIdx.x;  // 65536
    int o = i >> 10, idx = i & 1023;
    int r = ((idx >> 6) & 3) * 4 + (idx & 3);
    int p = (idx >> 8) * 16 + ((idx >> 2) & 15);
    WbP[i] = (half_t)Wb[(size_t)(r * 64 + p) * 64 + o];
}

// WuP[oc][o] = f16(Wu[o][oc])  (256 x 64)
__global__ void prep_wu(const float* __restrict__ Wu, half_t* __restrict__ WuP) {
    int i = blockIdx.x * 256 + threadIdx.x;  // 16384
    int oc = i >> 6, o = i & 63;
    WuP[i] = (half_t)Wu[(size_t)o * 256 + oc];
}

// ---------------------------------------------------------------------------
// Fused steps 3-5, MFMA f16. 16 atoms / block, 8 waves, 512 threads.
//  phase 1: wave w -> atoms {2w, 2w+1}           (einsum via identity-transpose)
//  phase 2: wave w -> o-tile w>>1, K-half w&1    (split-K, 4 accumulators)
//  phase 3: wave w -> oc in [w*32, w*32+32)
// ---------------------------------------------------------------------------
__global__ __launch_bounds__(512, 6) void fused(const half_t* __restrict__ xbh,
                                                const float*  __restrict__ rad,   // (N,16,32) f32
                                                const int*    __restrict__ sidxg, // (N,32)
                                                const half_t* __restrict__ WbP,   // (64,1024) permuted
                                                const half_t* __restrict__ WuP,   // (256,64) transposed
                                                float* __restrict__ out) {        // (N,256)
    __shared__ __align__(16) half_t xba2s[16 * 1024];   // 32 KB, rows XOR-swizzled
    __shared__ __align__(16) float  preds[2 * 16 * 68]; // 8.5 KB split-K partials
    __shared__ __align__(16) half_t houts[16 * 64];     //  2 KB, rows XOR-swizzled
    __shared__ int sidx_s[16 * KMAX];                   //  2 KB

    const int t = threadIdx.x;
    const int w = t >> 6;        // wave 0..7
    const int l = t & 63;
    const int c = l & 15;        // lane col within 16-group
    const int g = l >> 4;        // 16-lane group 0..3
    const int a0 = blockIdx.x * 16;

    // wave-private sidx staging: wave w loads exactly rows of its own atoms.
    sidx_s[t] = sidxg[(size_t)a0 * KMAX + t];
    // no __syncthreads needed: each wave reads only what it wrote (lgkmcnt order)

    const f32x4 fzero = {0.f, 0.f, 0.f, 0.f};

    // identity B-frag: B[k][n] = (k==n)
    half4_t ident;
    #pragma unroll
    for (int j = 0; j < 4; ++j) ident[j] = (half_t)((g * 4 + j == c) ? 1.0f : 0.0f);

    // ---------------- phase 1: xba2 = rad @ x2, 2 atoms per wave -------------
    #pragma unroll
    for (int as = 0; as < 2; ++as) {
        const int a = w * 2 + as;  // local atom 0..15
        const float* radp = &rad[(size_t)(a0 + a) * 512];

        // rad A-frags: A[m=r=c][k] = rad[c][kc*16 + g*4+j]
        half4_t radF[2];
        #pragma unroll
        for (int kc = 0; kc < 2; ++kc) {
            f32x4 rv = *reinterpret_cast<const f32x4*>(radp + c * 32 + kc * 16 + g * 4);
            #pragma unroll
            for (int j = 0; j < 4; ++j) radF[kc][j] = (half_t)rv[j];
        }

        f32x4 acc[4] = {fzero, fzero, fzero, fzero};  // 4 p-chunks of 16
        #pragma unroll
        for (int kc = 0; kc < 2; ++kc) {
            int s = sidx_s[a * KMAX + kc * 16 + c];   // row source for x2 k-row
            const half_t* srow = &xbh[(size_t)(s < 0 ? 0 : s) * 64];
            #pragma unroll
            for (int pc = 0; pc < 4; ++pc) {
                // gather chunk in A-layout: A[m=c][k=g*4+j] = x2[kc*16+c][pc*16+g*4+j]
                half4_t gf = {(half_t)0, (half_t)0, (half_t)0, (half_t)0};
                if (s >= 0)
                    gf = *reinterpret_cast<const half4_t*>(srow + pc * 16 + g * 4);
                // layout-convert A-frag -> B-frag via identity mfma (exact)
                f32x4 tD = __builtin_amdgcn_mfma_f32_16x16x16f16(gf, ident, fzero, 0, 0, 0);
                half4_t b2;
                #pragma unroll
                for (int j = 0; j < 4; ++j) b2[j] = (half_t)tD[j];
                acc[pc] = __builtin_amdgcn_mfma_f32_16x16x16f16(radF[kc], b2, acc[pc], 0, 0, 0);
            }
        }
        // lane holds (r=g*4+i, p=pc*16+c); idx = pc*256+g*64+c*4+i, row-swizzled
        #pragma unroll
        for (int pc = 0; pc < 4; ++pc) {
            half4_t hv;
            #pragma unroll
            for (int j = 0; j < 4; ++j) hv[j] = (half_t)acc[pc][j];
            int byte = (a * 2048 + pc * 512 + g * 128 + c * 8) ^ ((a & 7) << 4);
            *reinterpret_cast<half4_t*>(reinterpret_cast<char*>(xba2s) + byte) = hv;
        }
    }
    __syncthreads();

    // ---------------- phase 2: h_out(16x64) = xba2(16x1024) @ WbP^T ----------
    // wave w: o = (w>>1)*16 + c, K-half kh = w&1; 16 steps, 4 rotating accs.
    {
        const int ot = w >> 1, kh = w & 1;
        f32x4 acc2[4] = {fzero, fzero, fzero, fzero};
        const half_t* wbrow = &WbP[(size_t)(ot * 16 + c) * 1024];
        #pragma unroll
        for (int j = 0; j < 16; ++j) {
            int K0 = kh * 512 + j * 32;
            int abyte = (c * 2048 + K0 * 2 + g * 16) ^ ((c & 7) << 4);  // atom row = c
            half8_t af = *reinterpret_cast<const half8_t*>(
                reinterpret_cast<const char*>(xba2s) + abyte);
            half8_t bf = *reinterpret_cast<const half8_t*>(wbrow + K0 + g * 8);
            acc2[j & 3] = __builtin_amdgcn_mfma_f32_16x16x32_f16(af, bf, acc2[j & 3], 0, 0, 0);
        }
        f32x4 accT = acc2[0] + acc2[1] + acc2[2] + acc2[3];
        // preds[kh][m=g*4+i][o=ot*16+c], row stride 68 (bank-spread)
        #pragma unroll
        for (int i = 0; i < 4; ++i)
            preds[kh * 1088 + (g * 4 + i) * 68 + ot * 16 + c] = accT[i];
    }
    __syncthreads();

    // reduce split-K partials -> houts f16 (row-swizzled)
    {
        int m = t >> 5, oj = (t & 31) << 1;
        float s0 = preds[m * 68 + oj]     + preds[1088 + m * 68 + oj];
        float s1 = preds[m * 68 + oj + 1] + preds[1088 + m * 68 + oj + 1];
        half2_t hv; hv[0] = (half_t)s0; hv[1] = (half_t)s1;
        int byte = (m * 128 + oj * 2) ^ ((m & 7) << 4);
        *reinterpret_cast<half2_t*>(reinterpret_cast<char*>(houts) + byte) = hv;
    }
    __syncthreads();

    // ---------------- phase 3: out(16x256) = hout(16x64) @ WuP^T -------------
    // wave w -> oc in [w*32, w*32+32); A row m = atom = c; K = 64.
    half8_t ha[2];
    #pragma unroll
    for (int kk = 0; kk < 2; ++kk) {
        int byte = (c * 128 + kk * 64 + g * 16) ^ ((c & 7) << 4);
        ha[kk] = *reinterpret_cast<const half8_t*>(
            reinterpret_cast<const char*>(houts) + byte);
    }
    #pragma unroll
    for (int nt = 0; nt < 2; ++nt) {
        int oc0 = w * 32 + nt * 16;
        f32x4 acc3 = fzero;
        #pragma unroll
        for (int kk = 0; kk < 2; ++kk) {
            half8_t bf = *reinterpret_cast<const half8_t*>(
                &WuP[(size_t)(oc0 + c) * 64 + kk * 32 + g * 8]);
            acc3 = __builtin_amdgcn_mfma_f32_16x16x32_f16(ha[kk], bf, acc3, 0, 0, 0);
        }
        #pragma unroll
        for (int i = 0; i < 4; ++i)
            out[(size_t)(a0 + g * 4 + i) * 256 + oc0 + c] = acc3[i];
    }
}

// ---------------------------------------------------------------------------
extern "C" void kernel_launch(void* const* d_in, const int* in_sizes, int n_in,
                              void* d_out, int out_size, void* d_ws, size_t ws_size,
                              hipStream_t stream) {
    const float* h   = (const float*)d_in[0];
    const float* rad = (const float*)d_in[1];
    const int*   ei  = (const int*)d_in[2];
    const int*   tni = (const int*)d_in[3];
    const float* Wd  = (const float*)d_in[4];
    const float* Wb  = (const float*)d_in[5];
    const float* Wu  = (const float*)d_in[6];
    float* out = (float*)d_out;

    // workspace: xbh f16 (6.4MB) | sidx i32 (6.4MB) | WbP f16 (128KB) | WuP f16 (32KB)
    half_t* xbh  = (half_t*)d_ws;
    int*    sidx = (int*)((char*)d_ws + (size_t)N_ATOMS * EP_IN * sizeof(half_t));
    half_t* WbP  = (half_t*)((char*)sidx + (size_t)NEDGES * sizeof(int));
    half_t* WuP  = WbP + 64 * 1024;

    xb_gemm<<<(N_ATOMS + 63) / 64, 256, 0, stream>>>(h, Wd, xbh);
    init_sidx<<<(NEDGES + 255) / 256, 256, 0, stream>>>(sidx);
    scatter_sidx<<<(NEDGES + 255) / 256, 256, 0, stream>>>(ei, tni, sidx);
    prep_wb<<<256, 256, 0, stream>>>(Wb, WbP);
    prep_wu<<<64, 256, 0, stream>>>(Wu, WuP);
    fused<<<N_ATOMS / 16, 512, 0, stream>>>(xbh, rad, sidx, WbP, WuP, out);
}

// Round 3
// 104.778 us; speedup vs baseline: 3.6913x; 1.6117x over previous
//
#include <hip/hip_runtime.h>

#define N_ATOMS 50000
#define KMAX 32
#define EMB_ATOM 256
#define EP_IN 64
#define EP_OUT 64
#define EMB_RBF 16
#define NEDGES (N_ATOMS * KMAX)

typedef _Float16 half_t;
typedef __attribute__((ext_vector_type(2))) _Float16 half2_t;
typedef __attribute__((ext_vector_type(4))) _Float16 half4_t;
typedef __attribute__((ext_vector_type(8))) _Float16 half8_t;
typedef __attribute__((ext_vector_type(4))) float f32x4;

static_assert(N_ATOMS % 16 == 0, "fused kernel assumes 16 atoms per block");
static_assert(sizeof(half4_t) == 8 && sizeof(half8_t) == 16, "vector sizes");

#define GLOAD_LDS16(g, l)                                                     \
    __builtin_amdgcn_global_load_lds(                                         \
        (const __attribute__((address_space(1))) void*)(g),                   \
        (__attribute__((address_space(3))) void*)(l), 16, 0, 0)

// ---------------------------------------------------------------------------
// Kernel A: x_b = h @ W_down  (50000x256)@(256x64) -> (50000x64), stored f16.
// ---------------------------------------------------------------------------
__global__ __launch_bounds__(256) void xb_gemm(const float* __restrict__ h,
                                               const float* __restrict__ Wd,
                                               half_t* __restrict__ xbh) {
    __shared__ float As[16 * 68];  // [k][m], stride 68
    __shared__ float Bs[16 * 64];  // [k][n]
    const int t = threadIdx.x;
    const int r0 = blockIdx.x * 64;
    const int tr = t >> 4;
    const int tc = t & 15;
    float acc[4][4] = {};

    for (int k0 = 0; k0 < 256; k0 += 16) {
        {
            int m = t >> 2, kk0 = (t & 3) << 2;
            int row = r0 + m;
            float4 v = make_float4(0.f, 0.f, 0.f, 0.f);
            if (row < N_ATOMS)
                v = *reinterpret_cast<const float4*>(&h[(size_t)row * 256 + k0 + kk0]);
            As[(kk0 + 0) * 68 + m] = v.x;
            As[(kk0 + 1) * 68 + m] = v.y;
            As[(kk0 + 2) * 68 + m] = v.z;
            As[(kk0 + 3) * 68 + m] = v.w;
        }
        {
            int kk = t >> 4, n0 = (t & 15) << 2;
            *reinterpret_cast<float4*>(&Bs[kk * 64 + n0]) =
                *reinterpret_cast<const float4*>(&Wd[(k0 + kk) * 64 + n0]);
        }
        __syncthreads();
        #pragma unroll
        for (int kk = 0; kk < 16; ++kk) {
            float4 av = *reinterpret_cast<const float4*>(&As[kk * 68 + tr * 4]);
            float4 bv = *reinterpret_cast<const float4*>(&Bs[kk * 64 + tc * 4]);
            float aa[4] = {av.x, av.y, av.z, av.w};
            float bb[4] = {bv.x, bv.y, bv.z, bv.w};
            #pragma unroll
            for (int i = 0; i < 4; ++i)
                #pragma unroll
                for (int j = 0; j < 4; ++j) acc[i][j] += aa[i] * bb[j];
        }
        __syncthreads();
    }
    #pragma unroll
    for (int i = 0; i < 4; ++i) {
        int row = r0 + tr * 4 + i;
        if (row < N_ATOMS) {
            half4_t hv;
            #pragma unroll
            for (int j = 0; j < 4; ++j) hv[j] = (half_t)acc[i][j];
            *reinterpret_cast<half4_t*>(&xbh[(size_t)row * 64 + tc * 4]) = hv;
        }
    }
}

// ---------------------------------------------------------------------------
// Kernels B/C: srcidx[atom][k] = source atom (-1 = zero row); zero pad row
// ---------------------------------------------------------------------------
__global__ void init_sidx(int* __restrict__ sidx) {
    int i = blockIdx.x * 256 + threadIdx.x;
    if (i < NEDGES) sidx[i] = -1;
}

__global__ void scatter_sidx(const int* __restrict__ ei, const int* __restrict__ tni,
                             int* __restrict__ sidx) {
    int i = blockIdx.x * 256 + threadIdx.x;
    if (i < NEDGES) {
        int s = ei[i];
        int d = ei[NEDGES + i];
        int k = tni[i];
        sidx[d * KMAX + k] = s;
    }
}

__global__ void zero_pad(half_t* __restrict__ z) {
    z[threadIdx.x] = (half_t)0.f;  // 128 halves = one zero xbh row
}

// ---------------------------------------------------------------------------
// Prep: Wb2 in per-instruction-linear order for the fused phase-2 loads.
// Fused reads, for (ot, kh, j), lane l, elems e: contiguous 16B per lane.
//   flat i: e=i&7 | l=(i>>3)&63 | j=(i>>9)&15 | kh=(i>>13)&1 | ot=i>>14
//   logical: o = ot*16 + (l&15); idx = kh*512 + j*32 + (l>>4)*8 + e
//   idx <-> (r,p): r = ((idx>>6)&3)*4 + (idx&3); p = (idx>>8)*16 + ((idx>>2)&15)
// ---------------------------------------------------------------------------
__global__ void prep_wb(const float* __restrict__ Wb, half_t* __restrict__ Wb2) {
    int i = blockIdx.x * 256 + threadIdx.x;  // 65536
    int e = i & 7, lv = (i >> 3) & 63, j = (i >> 9) & 15;
    int kh = (i >> 13) & 1, ot = i >> 14;
    int c = lv & 15, g = lv >> 4;
    int o = ot * 16 + c;
    int idx = kh * 512 + j * 32 + g * 8 + e;
    int r = ((idx >> 6) & 3) * 4 + (idx & 3);
    int p = (idx >> 8) * 16 + ((idx >> 2) & 15);
    Wb2[i] = (half_t)Wb[(size_t)(r * 64 + p) * 64 + o];
}

// Wu2 per-instruction-linear: flat i: e=i&7 | l=(i>>3)&63 | kk=(i>>9)&1 |
//   nt=(i>>10)&1 | w=i>>11 ; oc = w*32+nt*16+(l&15); o = kk*32+(l>>4)*8+e
__global__ void prep_wu(const float* __restrict__ Wu, half_t* __restrict__ Wu2) {
    int i = blockIdx.x * 256 + threadIdx.x;  // 16384
    int e = i & 7, lv = (i >> 3) & 63, kk = (i >> 9) & 1;
    int nt = (i >> 10) & 1, w = i >> 11;
    int c = lv & 15, g = lv >> 4;
    int oc = w * 32 + nt * 16 + c;
    int o = kk * 32 + g * 8 + e;
    Wu2[i] = (half_t)Wu[(size_t)o * 256 + oc];
}

// ---------------------------------------------------------------------------
// Fused steps 3-5, MFMA f16. 16 atoms / block, 8 waves, 512 threads.
//  phase 1: wave w -> atoms {2w, 2w+1}; x2 rows staged via global_load_lds
//           (wave-private 2KB region, 1 line per gathered row, source-side
//           XOR-chunk swizzle for conflict-free ds_read consume)
//  phase 2: wave w -> o-tile w>>1, K-half w&1 (split-K); Wb2 coalesced 1KB/instr
//  phase 3: wave w -> oc in [w*32, w*32+32); Wu2 coalesced
// ---------------------------------------------------------------------------
__global__ __launch_bounds__(512, 6) void fused(const half_t* __restrict__ xbh,
                                                const float*  __restrict__ rad,   // (N,16,32) f32
                                                const int*    __restrict__ sidxg, // (N,32)
                                                const half_t* __restrict__ Wb2,   // (65536) permuted
                                                const half_t* __restrict__ Wu2,   // (16384) permuted
                                                const half_t* __restrict__ zrow,  // 128 zero f16
                                                float* __restrict__ out) {        // (N,256)
    __shared__ __align__(16) half_t xba2s[16 * 1024];   // 32 KB, rows XOR-swizzled
    __shared__ __align__(16) char   smem_u[16384];      // 16 KB: stage (ph1) / preds+houts (ph2)
    __shared__ int sidx_s[16 * KMAX];                   //  2 KB

    const int t = threadIdx.x;
    const int w = t >> 6;        // wave 0..7
    const int l = t & 63;
    const int c = l & 15;        // lane col within 16-group
    const int g = l >> 4;        // 16-lane group 0..3
    const int a0 = blockIdx.x * 16;

    float*  preds = reinterpret_cast<float*>(smem_u);            // 2*16*68*4 = 8704 B (phase 2)
    half_t* houts = reinterpret_cast<half_t*>(smem_u + 8704);    // 2048 B swizzled (phase 2)
    half_t* stage = reinterpret_cast<half_t*>(smem_u + (w << 11)); // 2 KB/wave (phase 1)

    // wave-private sidx staging: wave w loads exactly its own atoms' rows.
    sidx_s[t] = sidxg[(size_t)a0 * KMAX + t];

    const f32x4 fzero = {0.f, 0.f, 0.f, 0.f};

    // identity B-frag: B[k][n] = (k==n)
    half4_t ident;
    #pragma unroll
    for (int j = 0; j < 4; ++j) ident[j] = (half_t)((g * 4 + j == c) ? 1.0f : 0.0f);

    // ---------------- phase 1: xba2 = rad @ x2, 2 atoms per wave -------------
    #pragma unroll
    for (int as = 0; as < 2; ++as) {
        const int a = w * 2 + as;  // local atom 0..15
        const float* radp = &rad[(size_t)(a0 + a) * 512];

        // rad A-frags: A[m=r=c][k] = rad[c][kc*16 + g*4+j]
        half4_t radF[2];
        #pragma unroll
        for (int kc = 0; kc < 2; ++kc) {
            f32x4 rv = *reinterpret_cast<const f32x4*>(radp + c * 32 + kc * 16 + g * 4);
            #pragma unroll
            for (int j = 0; j < 4; ++j) radF[kc][j] = (half_t)rv[j];
        }

        f32x4 acc[4] = {fzero, fzero, fzero, fzero};  // 4 p-chunks of 16
        #pragma unroll
        for (int kc = 0; kc < 2; ++kc) {
            // drain pending ds_reads of previous batch before overwriting stage
            asm volatile("s_waitcnt lgkmcnt(0)" ::: "memory");
            // stage 16 gathered rows (one kc-half): 2 x global_load_lds, 16B/lane.
            // row r_ = h*8 + (l>>3), chunk slot = l&7; source chunk pre-swizzled
            // so LDS[r_][slot] = srcrow[slot ^ (r_&7)]  (linear LDS dest).
            #pragma unroll
            for (int h = 0; h < 2; ++h) {
                int r_ = h * 8 + (l >> 3);
                int s = sidx_s[a * KMAX + kc * 16 + r_];
                const half_t* src = (s >= 0) ? (xbh + (size_t)s * 64) : zrow;
                src += (((l & 7) ^ (r_ & 7)) << 3);  // swizzled 16B chunk
                GLOAD_LDS16(src, stage + (h << 9));  // h*512 halves = 1024 B
            }
            asm volatile("s_waitcnt vmcnt(0)" ::: "memory");
            __builtin_amdgcn_sched_barrier(0);
            const char* stb = reinterpret_cast<const char*>(stage);
            #pragma unroll
            for (int pc = 0; pc < 4; ++pc) {
                // A-layout chunk: A[m=c][k=g*4+j] = x2[kc*16+c][pc*16+g*4+j]
                int slot = (pc * 2 + (g >> 1)) ^ (c & 7);
                half4_t gf = *reinterpret_cast<const half4_t*>(
                    stb + c * 128 + slot * 16 + (g & 1) * 8);
                // layout-convert A-frag -> B-frag via identity mfma (exact)
                f32x4 tD = __builtin_amdgcn_mfma_f32_16x16x16f16(gf, ident, fzero, 0, 0, 0);
                half4_t b2;
                #pragma unroll
                for (int j = 0; j < 4; ++j) b2[j] = (half_t)tD[j];
                acc[pc] = __builtin_amdgcn_mfma_f32_16x16x16f16(radF[kc], b2, acc[pc], 0, 0, 0);
            }
        }
        // lane holds (r=g*4+i, p=pc*16+c); idx = pc*256+g*64+c*4+i, row-swizzled
        #pragma unroll
        for (int pc = 0; pc < 4; ++pc) {
            half4_t hv;
            #pragma unroll
            for (int j = 0; j < 4; ++j) hv[j] = (half_t)acc[pc][j];
            int byte = (a * 2048 + pc * 512 + g * 128 + c * 8) ^ ((a & 7) << 4);
            *reinterpret_cast<half4_t*>(reinterpret_cast<char*>(xba2s) + byte) = hv;
        }
    }
    __syncthreads();

    // ---------------- phase 2: h_out(16x64) = xba2(16x1024) @ Wb ------------
    // wave w: o = (w>>1)*16 + c, K-half kh = w&1; 16 steps, 4 rotating accs.
    {
        const int ot = w >> 1, kh = w & 1;
        f32x4 acc2[4] = {fzero, fzero, fzero, fzero};
        const half_t* wbbase = &Wb2[(size_t)((ot * 2 + kh) * 16) * 512];
        #pragma unroll
        for (int j = 0; j < 16; ++j) {
            int K0 = kh * 512 + j * 32;
            int abyte = (c * 2048 + K0 * 2 + g * 16) ^ ((c & 7) << 4);  // atom row = c
            half8_t af = *reinterpret_cast<const half8_t*>(
                reinterpret_cast<const char*>(xba2s) + abyte);
            half8_t bf = *reinterpret_cast<const half8_t*>(wbbase + j * 512 + l * 8);
            acc2[j & 3] = __builtin_amdgcn_mfma_f32_16x16x32_f16(af, bf, acc2[j & 3], 0, 0, 0);
        }
        f32x4 accT = acc2[0] + acc2[1] + acc2[2] + acc2[3];
        // preds[kh][m=g*4+i][o=ot*16+c], row stride 68 (bank-spread)
        #pragma unroll
        for (int i = 0; i < 4; ++i)
            preds[kh * 1088 + (g * 4 + i) * 68 + ot * 16 + c] = accT[i];
    }
    __syncthreads();

    // reduce split-K partials -> houts f16 (row-swizzled)
    {
        int m = t >> 5, oj = (t & 31) << 1;
        float s0 = preds[m * 68 + oj]     + preds[1088 + m * 68 + oj];
        float s1 = preds[m * 68 + oj + 1] + preds[1088 + m * 68 + oj + 1];
        half2_t hv; hv[0] = (half_t)s0; hv[1] = (half_t)s1;
        int byte = (m * 128 + oj * 2) ^ ((m & 7) << 4);
        *reinterpret_cast<half2_t*>(reinterpret_cast<char*>(houts) + byte) = hv;
    }
    __syncthreads();

    // ---------------- phase 3: out(16x256) = hout(16x64) @ Wu ---------------
    // wave w -> oc in [w*32, w*32+32); A row m = atom = c; K = 64.
    half8_t ha[2];
    #pragma unroll
    for (int kk = 0; kk < 2; ++kk) {
        int byte = (c * 128 + kk * 64 + g * 16) ^ ((c & 7) << 4);
        ha[kk] = *reinterpret_cast<const half8_t*>(
            reinterpret_cast<const char*>(houts) + byte);
    }
    #pragma unroll
    for (int nt = 0; nt < 2; ++nt) {
        int oc0 = w * 32 + nt * 16;
        f32x4 acc3 = fzero;
        #pragma unroll
        for (int kk = 0; kk < 2; ++kk) {
            half8_t bf = *reinterpret_cast<const half8_t*>(
                &Wu2[(size_t)(((w * 2 + nt) * 2 + kk) * 64 + l) * 8]);
            acc3 = __builtin_amdgcn_mfma_f32_16x16x32_f16(ha[kk], bf, acc3, 0, 0, 0);
        }
        #pragma unroll
        for (int i = 0; i < 4; ++i)
            out[(size_t)(a0 + g * 4 + i) * 256 + oc0 + c] = acc3[i];
    }
}

// ---------------------------------------------------------------------------
extern "C" void kernel_launch(void* const* d_in, const int* in_sizes, int n_in,
                              void* d_out, int out_size, void* d_ws, size_t ws_size,
                              hipStream_t stream) {
    const float* h   = (const float*)d_in[0];
    const float* rad = (const float*)d_in[1];
    const int*   ei  = (const int*)d_in[2];
    const int*   tni = (const int*)d_in[3];
    const float* Wd  = (const float*)d_in[4];
    const float* Wb  = (const float*)d_in[5];
    const float* Wu  = (const float*)d_in[6];
    float* out = (float*)d_out;

    // workspace: xbh f16 6.4MB | sidx i32 6.4MB | Wb2 128KB | Wu2 32KB | zrow 256B
    half_t* xbh  = (half_t*)d_ws;
    int*    sidx = (int*)((char*)d_ws + (size_t)N_ATOMS * EP_IN * sizeof(half_t));
    half_t* Wb2  = (half_t*)((char*)sidx + (size_t)NEDGES * sizeof(int));
    half_t* Wu2  = Wb2 + 64 * 1024;
    half_t* zrow = Wu2 + 16384;

    xb_gemm<<<(N_ATOMS + 63) / 64, 256, 0, stream>>>(h, Wd, xbh);
    init_sidx<<<(NEDGES + 255) / 256, 256, 0, stream>>>(sidx);
    scatter_sidx<<<(NEDGES + 255) / 256, 256, 0, stream>>>(ei, tni, sidx);
    zero_pad<<<1, 128, 0, stream>>>(zrow);
    prep_wb<<<256, 256, 0, stream>>>(Wb, Wb2);
    prep_wu<<<64, 256, 0, stream>>>(Wu, Wu2);
    fused<<<N_ATOMS / 16, 512, 0, stream>>>(xbh, rad, sidx, Wb2, Wu2, zrow, out);
}

// Round 4
// 88.256 us; speedup vs baseline: 4.3824x; 1.1872x over previous
//
#include <hip/hip_runtime.h>

#define N_ATOMS 50000
#define KMAX 32
#define EMB_ATOM 256
#define EP_IN 64
#define EP_OUT 64
#define EMB_RBF 16
#define NEDGES (N_ATOMS * KMAX)

typedef _Float16 half_t;
typedef __attribute__((ext_vector_type(2))) _Float16 half2_t;
typedef __attribute__((ext_vector_type(4))) _Float16 half4_t;
typedef __attribute__((ext_vector_type(8))) _Float16 half8_t;
typedef __attribute__((ext_vector_type(4))) float f32x4;

static_assert(N_ATOMS % 16 == 0, "fused kernel assumes 16 atoms per block");

#define GLOAD_LDS16(g, l)                                                     \
    __builtin_amdgcn_global_load_lds(                                         \
        (const __attribute__((address_space(1))) void*)(g),                   \
        (__attribute__((address_space(3))) void*)(l), 16, 0, 0)

// grid partition of prep_all
#define XB_NB 782                       // ceil(50000/64)
#define SC_NB (NEDGES / 256)            // 6250
#define WB_NB 256
#define WU_NB 64
#define PREP_NB (XB_NB + SC_NB + WB_NB + WU_NB + 1)

// ---------------------------------------------------------------------------
// prep_all: one launch for everything before `fused`.
//  blocks [0,782)       : x_b = h @ W_down -> f16 xbh
//  blocks [782,7032)    : scatter srcidx (input covers every (dst,slot))
//  blocks [7032,7288)   : Wb2 permuted f16
//  blocks [7288,7352)   : Wu2 permuted f16
//  block  7352          : zero pad row
// ---------------------------------------------------------------------------
__global__ __launch_bounds__(256) void prep_all(const float* __restrict__ h,
                                                const float* __restrict__ Wd,
                                                const int*   __restrict__ ei,
                                                const int*   __restrict__ tni,
                                                const float* __restrict__ Wb,
                                                const float* __restrict__ Wu,
                                                half_t* __restrict__ xbh,
                                                int*    __restrict__ sidx,
                                                half_t* __restrict__ Wb2,
                                                half_t* __restrict__ Wu2,
                                                half_t* __restrict__ zrow) {
    __shared__ float As[16 * 68];
    __shared__ float Bs[16 * 64];
    const int bid = blockIdx.x;
    const int t = threadIdx.x;

    if (bid < XB_NB) {
        // ---- x_b GEMM: 64x64 tile, fp32 compute, f16 store ----
        const int r0 = bid * 64;
        const int tr = t >> 4, tc = t & 15;
        float acc[4][4] = {};
        for (int k0 = 0; k0 < 256; k0 += 16) {
            {
                int m = t >> 2, kk0 = (t & 3) << 2;
                int row = r0 + m;
                float4 v = make_float4(0.f, 0.f, 0.f, 0.f);
                if (row < N_ATOMS)
                    v = *reinterpret_cast<const float4*>(&h[(size_t)row * 256 + k0 + kk0]);
                As[(kk0 + 0) * 68 + m] = v.x;
                As[(kk0 + 1) * 68 + m] = v.y;
                As[(kk0 + 2) * 68 + m] = v.z;
                As[(kk0 + 3) * 68 + m] = v.w;
            }
            {
                int kk = t >> 4, n0 = (t & 15) << 2;
                *reinterpret_cast<float4*>(&Bs[kk * 64 + n0]) =
                    *reinterpret_cast<const float4*>(&Wd[(k0 + kk) * 64 + n0]);
            }
            __syncthreads();
            #pragma unroll
            for (int kk = 0; kk < 16; ++kk) {
                float4 av = *reinterpret_cast<const float4*>(&As[kk * 68 + tr * 4]);
                float4 bv = *reinterpret_cast<const float4*>(&Bs[kk * 64 + tc * 4]);
                float aa[4] = {av.x, av.y, av.z, av.w};
                float bb[4] = {bv.x, bv.y, bv.z, bv.w};
                #pragma unroll
                for (int i = 0; i < 4; ++i)
                    #pragma unroll
                    for (int j = 0; j < 4; ++j) acc[i][j] += aa[i] * bb[j];
            }
            __syncthreads();
        }
        #pragma unroll
        for (int i = 0; i < 4; ++i) {
            int row = r0 + tr * 4 + i;
            if (row < N_ATOMS) {
                half4_t hv;
                #pragma unroll
                for (int j = 0; j < 4; ++j) hv[j] = (half_t)acc[i][j];
                *reinterpret_cast<half4_t*>(&xbh[(size_t)row * 64 + tc * 4]) = hv;
            }
        }
    } else if (bid < XB_NB + SC_NB) {
        int i = (bid - XB_NB) * 256 + t;
        int s = ei[i];
        int d = ei[NEDGES + i];
        int k = tni[i];
        sidx[d * KMAX + k] = s;
    } else if (bid < XB_NB + SC_NB + WB_NB) {
        // Wb2[i]: e=i&7 | l=(i>>3)&63 | j=(i>>9)&15 | kh=(i>>13)&1 | ot=i>>14
        int i = (bid - XB_NB - SC_NB) * 256 + t;
        int e = i & 7, lv = (i >> 3) & 63;
        int c = lv & 15, g = lv >> 4;
        int kh = (i >> 13) & 1, ot = i >> 14;
        int o = ot * 16 + c;
        int idx = kh * 512 + ((i >> 9) & 15) * 32 + g * 8 + e;
        int r = ((idx >> 6) & 3) * 4 + (idx & 3);
        int p = (idx >> 8) * 16 + ((idx >> 2) & 15);
        Wb2[i] = (half_t)Wb[(size_t)(r * 64 + p) * 64 + o];
    } else if (bid < XB_NB + SC_NB + WB_NB + WU_NB) {
        // Wu2[i]: e=i&7 | l=(i>>3)&63 | kk=(i>>9)&1 | nt=(i>>10)&1 | w=i>>11
        int i = (bid - XB_NB - SC_NB - WB_NB) * 256 + t;
        int e = i & 7, lv = (i >> 3) & 63;
        int c = lv & 15, g = lv >> 4;
        int kk = (i >> 9) & 1, nt = (i >> 10) & 1, w = i >> 11;
        int oc = w * 32 + nt * 16 + c;
        int o = kk * 32 + g * 8 + e;
        Wu2[i] = (half_t)Wu[(size_t)o * 256 + oc];
    } else {
        if (t < 128) zrow[t] = (half_t)0.f;
    }
}

// ---------------------------------------------------------------------------
// consume one staged kc-batch (16 gathered rows) from buffer BUF
// ---------------------------------------------------------------------------
template <int BUF>
__device__ __forceinline__ void consume_batch(const half_t* stage_h, int c, int g,
                                              half4_t radf, half4_t ident,
                                              f32x4 (&acc)[4]) {
    const f32x4 fzero = {0.f, 0.f, 0.f, 0.f};
    const char* stb = reinterpret_cast<const char*>(stage_h) + BUF * 2048;
    #pragma unroll
    for (int pc = 0; pc < 4; ++pc) {
        int slot = (pc * 2 + (g >> 1)) ^ (c & 7);
        half4_t gf = *reinterpret_cast<const half4_t*>(
            stb + c * 128 + slot * 16 + (g & 1) * 8);
        // layout-convert A-frag -> B-frag via identity mfma (exact)
        f32x4 tD = __builtin_amdgcn_mfma_f32_16x16x16f16(gf, ident, fzero, 0, 0, 0);
        half4_t b2;
        #pragma unroll
        for (int j = 0; j < 4; ++j) b2[j] = (half_t)tD[j];
        acc[pc] = __builtin_amdgcn_mfma_f32_16x16x16f16(radf, b2, acc[pc], 0, 0, 0);
    }
}

// issue one kc-batch (2 x global_load_lds, 1 KB each) into buffer `buf`
#define ISSUE(b, buf) do {                                                    \
    { int s_ = sreg[(b) * 2 + 0]; int r_ = (l >> 3);                          \
      const half_t* src_ = ((unsigned)s_ < (unsigned)N_ATOMS)                 \
          ? (xbh + (size_t)s_ * 64) : zrow;                                   \
      src_ += (((l & 7) ^ (r_ & 7)) << 3);                                    \
      GLOAD_LDS16(src_, stage_h + (buf) * 1024); }                            \
    { int s_ = sreg[(b) * 2 + 1]; int r_ = 8 + (l >> 3);                      \
      const half_t* src_ = ((unsigned)s_ < (unsigned)N_ATOMS)                 \
          ? (xbh + (size_t)s_ * 64) : zrow;                                   \
      src_ += (((l & 7) ^ (r_ & 7)) << 3);                                    \
      GLOAD_LDS16(src_, stage_h + (buf) * 1024 + 512); }                      \
} while (0)

#define WAIT_VM(n) do {                                                       \
    asm volatile("s_waitcnt vmcnt(" #n ")" ::: "memory");                     \
    __builtin_amdgcn_sched_barrier(0);                                        \
} while (0)

#define WAIT_LGKM() do {                                                      \
    asm volatile("s_waitcnt lgkmcnt(0)" ::: "memory");                        \
    __builtin_amdgcn_sched_barrier(0);                                        \
} while (0)

// ---------------------------------------------------------------------------
// Fused steps 3-5, MFMA f16. 16 atoms / block, 8 waves, 512 threads.
//  phase 1: wave w -> atoms {2w, 2w+1}; gathers via global_load_lds,
//           double-buffered + counted-vmcnt pipeline (depth 2)
//  phase 2: wave w -> o-tile w>>1, K-half w&1 (split-K); Wb2 reg-prefetch x4
//  phase 3: wave w -> oc in [w*32,+32); Wu2 prefetched across the barrier
// ---------------------------------------------------------------------------
__global__ __launch_bounds__(512, 4) void fused(const half_t* __restrict__ xbh,
                                                const float*  __restrict__ rad,   // (N,16,32) f32
                                                const int*    __restrict__ sidxg, // (N,32)
                                                const half_t* __restrict__ Wb2,   // (65536) permuted
                                                const half_t* __restrict__ Wu2,   // (16384) permuted
                                                const half_t* __restrict__ zrow,  // 128 zero f16
                                                float* __restrict__ out) {        // (N,256)
    __shared__ __align__(16) half_t xba2s[16 * 1024];  // 32 KB, rows XOR-swizzled
    __shared__ __align__(16) char   smem_u[32768];     // 32 KB stage (ph1) / preds+houts (ph2+)

    const int t = threadIdx.x;
    const int w = t >> 6;        // wave 0..7
    const int l = t & 63;
    const int c = l & 15;
    const int g = l >> 4;
    const int a0 = blockIdx.x * 16;

    float*  preds   = reinterpret_cast<float*>(smem_u);              // 8704 B
    half_t* houts   = reinterpret_cast<half_t*>(smem_u + 8704);      // 2048 B
    half_t* stage_h = reinterpret_cast<half_t*>(smem_u + (w << 12)); // 4 KB/wave

    const f32x4 fzero = {0.f, 0.f, 0.f, 0.f};

    // ---- per-lane sidx (8 regs) + rad fragments for both atoms: issue all ----
    int sreg[4 * 2];
    #pragma unroll
    for (int b = 0; b < 4; ++b)
        #pragma unroll
        for (int hh = 0; hh < 2; ++hh)
            sreg[b * 2 + hh] = sidxg[(size_t)(a0 + w * 2 + (b >> 1)) * KMAX +
                                     (b & 1) * 16 + hh * 8 + (l >> 3)];

    half4_t radF[2][2];  // [as][kc]
    #pragma unroll
    for (int as = 0; as < 2; ++as) {
        const float* radp = &rad[(size_t)(a0 + w * 2 + as) * 512];
        #pragma unroll
        for (int kc = 0; kc < 2; ++kc) {
            f32x4 rv = *reinterpret_cast<const f32x4*>(radp + c * 32 + kc * 16 + g * 4);
            #pragma unroll
            for (int j = 0; j < 4; ++j) radF[as][kc][j] = (half_t)rv[j];
        }
    }

    half4_t ident;  // identity B-frag: B[k][n] = (k==n)
    #pragma unroll
    for (int j = 0; j < 4; ++j) ident[j] = (half_t)((g * 4 + j == c) ? 1.0f : 0.0f);

    // ---------------- phase 1: depth-2 pipelined gather + einsum -------------
    ISSUE(0, 0);
    ISSUE(1, 1);

    f32x4 acc[4] = {fzero, fzero, fzero, fzero};

    WAIT_VM(2);                                   // B0 landed
    consume_batch<0>(stage_h, c, g, radF[0][0], ident, acc);
    WAIT_LGKM();
    ISSUE(2, 0);

    WAIT_VM(2);                                   // B1 landed
    consume_batch<1>(stage_h, c, g, radF[0][1], ident, acc);
    // write atom (2w) results
    {
        const int a = w * 2;
        #pragma unroll
        for (int pc = 0; pc < 4; ++pc) {
            half4_t hv;
            #pragma unroll
            for (int j = 0; j < 4; ++j) hv[j] = (half_t)acc[pc][j];
            int byte = (a * 2048 + pc * 512 + g * 128 + c * 8) ^ ((a & 7) << 4);
            *reinterpret_cast<half4_t*>(reinterpret_cast<char*>(xba2s) + byte) = hv;
        }
    }
    WAIT_LGKM();
    ISSUE(3, 1);

    #pragma unroll
    for (int pc = 0; pc < 4; ++pc) acc[pc] = fzero;

    WAIT_VM(2);                                   // B2 landed
    consume_batch<0>(stage_h, c, g, radF[1][0], ident, acc);

    WAIT_VM(0);                                   // B3 landed
    consume_batch<1>(stage_h, c, g, radF[1][1], ident, acc);
    {
        const int a = w * 2 + 1;
        #pragma unroll
        for (int pc = 0; pc < 4; ++pc) {
            half4_t hv;
            #pragma unroll
            for (int j = 0; j < 4; ++j) hv[j] = (half_t)acc[pc][j];
            int byte = (a * 2048 + pc * 512 + g * 128 + c * 8) ^ ((a & 7) << 4);
            *reinterpret_cast<half4_t*>(reinterpret_cast<char*>(xba2s) + byte) = hv;
        }
    }

    // prefetch first 4 Wb2 fragments across the barrier
    const int ot = w >> 1, kh = w & 1;
    const half_t* wbbase = &Wb2[(size_t)((ot * 2 + kh) * 16) * 512];
    half8_t bfr[4];
    #pragma unroll
    for (int j = 0; j < 4; ++j)
        bfr[j] = *reinterpret_cast<const half8_t*>(wbbase + j * 512 + l * 8);

    __syncthreads();

    // ---------------- phase 2: h_out(16x64) = xba2(16x1024) @ Wb ------------
    {
        f32x4 acc2[4] = {fzero, fzero, fzero, fzero};
        #pragma unroll
        for (int j = 0; j < 16; ++j) {
            int abyte = (c * 2048 + (kh * 512 + j * 32) * 2 + g * 16) ^ ((c & 7) << 4);
            half8_t af = *reinterpret_cast<const half8_t*>(
                reinterpret_cast<const char*>(xba2s) + abyte);
            half8_t bf = bfr[j & 3];
            if (j + 4 < 16)
                bfr[j & 3] = *reinterpret_cast<const half8_t*>(wbbase + (j + 4) * 512 + l * 8);
            acc2[j & 3] = __builtin_amdgcn_mfma_f32_16x16x32_f16(af, bf, acc2[j & 3], 0, 0, 0);
        }
        f32x4 accT = acc2[0] + acc2[1] + acc2[2] + acc2[3];
        #pragma unroll
        for (int i = 0; i < 4; ++i)
            preds[kh * 1088 + (g * 4 + i) * 68 + ot * 16 + c] = accT[i];
    }

    // prefetch all 4 Wu2 fragments across the barrier
    half8_t wuf[2][2];
    #pragma unroll
    for (int nt = 0; nt < 2; ++nt)
        #pragma unroll
        for (int kk = 0; kk < 2; ++kk)
            wuf[nt][kk] = *reinterpret_cast<const half8_t*>(
                &Wu2[(size_t)(((w * 2 + nt) * 2 + kk) * 64 + l) * 8]);

    __syncthreads();

    // reduce split-K partials -> houts f16 (row-swizzled)
    {
        int m = t >> 5, oj = (t & 31) << 1;
        float s0 = preds[m * 68 + oj]     + preds[1088 + m * 68 + oj];
        float s1 = preds[m * 68 + oj + 1] + preds[1088 + m * 68 + oj + 1];
        half2_t hv; hv[0] = (half_t)s0; hv[1] = (half_t)s1;
        int byte = (m * 128 + oj * 2) ^ ((m & 7) << 4);
        *reinterpret_cast<half2_t*>(reinterpret_cast<char*>(houts) + byte) = hv;
    }
    __syncthreads();

    // ---------------- phase 3: out(16x256) = hout(16x64) @ Wu ---------------
    half8_t ha[2];
    #pragma unroll
    for (int kk = 0; kk < 2; ++kk) {
        int byte = (c * 128 + kk * 64 + g * 16) ^ ((c & 7) << 4);
        ha[kk] = *reinterpret_cast<const half8_t*>(
            reinterpret_cast<const char*>(houts) + byte);
    }
    #pragma unroll
    for (int nt = 0; nt < 2; ++nt) {
        int oc0 = w * 32 + nt * 16;
        f32x4 acc3 = fzero;
        #pragma unroll
        for (int kk = 0; kk < 2; ++kk)
            acc3 = __builtin_amdgcn_mfma_f32_16x16x32_f16(ha[kk], wuf[nt][kk], acc3, 0, 0, 0);
        #pragma unroll
        for (int i = 0; i < 4; ++i)
            out[(size_t)(a0 + g * 4 + i) * 256 + oc0 + c] = acc3[i];
    }
}

// ---------------------------------------------------------------------------
extern "C" void kernel_launch(void* const* d_in, const int* in_sizes, int n_in,
                              void* d_out, int out_size, void* d_ws, size_t ws_size,
                              hipStream_t stream) {
    const float* h   = (const float*)d_in[0];
    const float* rad = (const float*)d_in[1];
    const int*   ei  = (const int*)d_in[2];
    const int*   tni = (const int*)d_in[3];
    const float* Wd  = (const float*)d_in[4];
    const float* Wb  = (const float*)d_in[5];
    const float* Wu  = (const float*)d_in[6];
    float* out = (float*)d_out;

    // workspace: xbh f16 6.4MB | sidx i32 6.4MB | Wb2 128KB | Wu2 32KB | zrow 256B
    half_t* xbh  = (half_t*)d_ws;
    int*    sidx = (int*)((char*)d_ws + (size_t)N_ATOMS * EP_IN * sizeof(half_t));
    half_t* Wb2  = (half_t*)((char*)sidx + (size_t)NEDGES * sizeof(int));
    half_t* Wu2  = Wb2 + 64 * 1024;
    half_t* zrow = Wu2 + 16384;

    prep_all<<<PREP_NB, 256, 0, stream>>>(h, Wd, ei, tni, Wb, Wu,
                                          xbh, sidx, Wb2, Wu2, zrow);
    fused<<<N_ATOMS / 16, 512, 0, stream>>>(xbh, rad, sidx, Wb2, Wu2, zrow, out);
}

// Round 6
// 85.410 us; speedup vs baseline: 4.5284x; 1.0333x over previous
//
#include <hip/hip_runtime.h>

#define N_ATOMS 50000
#define KMAX 32
#define EMB_ATOM 256
#define EP_IN 64
#define EP_OUT 64
#define EMB_RBF 16
#define NEDGES (N_ATOMS * KMAX)

typedef _Float16 half_t;
typedef __attribute__((ext_vector_type(2))) _Float16 half2_t;
typedef __attribute__((ext_vector_type(4))) _Float16 half4_t;
typedef __attribute__((ext_vector_type(8))) _Float16 half8_t;
typedef __attribute__((ext_vector_type(4))) float f32x4;

static_assert(N_ATOMS % 16 == 0, "fused kernel assumes 16 atoms per block");

#define GLOAD_LDS16(g, l)                                                     \
    __builtin_amdgcn_global_load_lds(                                         \
        (const __attribute__((address_space(1))) void*)(g),                   \
        (__attribute__((address_space(3))) void*)(l), 16, 0, 0)

// grid partition of prep_all
#define XB_NB 782                       // ceil(50000/64)
#define SC_NB (NEDGES / 256)            // 6250
#define WB_NB 256
#define WU_NB 64
#define PREP_NB (XB_NB + SC_NB + WB_NB + WU_NB + 1)

// ---------------------------------------------------------------------------
// prep_all: one launch for everything before `fused`.
// ---------------------------------------------------------------------------
__global__ __launch_bounds__(256) void prep_all(const float* __restrict__ h,
                                                const float* __restrict__ Wd,
                                                const int*   __restrict__ ei,
                                                const int*   __restrict__ tni,
                                                const float* __restrict__ Wb,
                                                const float* __restrict__ Wu,
                                                half_t* __restrict__ xbh,
                                                int*    __restrict__ sidx,
                                                half_t* __restrict__ Wb2,
                                                half_t* __restrict__ Wu2,
                                                half_t* __restrict__ zrow) {
    __shared__ float As[16 * 68];
    __shared__ float Bs[16 * 64];
    const int bid = blockIdx.x;
    const int t = threadIdx.x;

    if (bid < XB_NB) {
        // ---- x_b GEMM: 64x64 tile, fp32 compute, f16 store ----
        const int r0 = bid * 64;
        const int tr = t >> 4, tc = t & 15;
        float acc[4][4] = {};
        for (int k0 = 0; k0 < 256; k0 += 16) {
            {
                int m = t >> 2, kk0 = (t & 3) << 2;
                int row = r0 + m;
                float4 v = make_float4(0.f, 0.f, 0.f, 0.f);
                if (row < N_ATOMS)
                    v = *reinterpret_cast<const float4*>(&h[(size_t)row * 256 + k0 + kk0]);
                As[(kk0 + 0) * 68 + m] = v.x;
                As[(kk0 + 1) * 68 + m] = v.y;
                As[(kk0 + 2) * 68 + m] = v.z;
                As[(kk0 + 3) * 68 + m] = v.w;
            }
            {
                int kk = t >> 4, n0 = (t & 15) << 2;
                *reinterpret_cast<float4*>(&Bs[kk * 64 + n0]) =
                    *reinterpret_cast<const float4*>(&Wd[(k0 + kk) * 64 + n0]);
            }
            __syncthreads();
            #pragma unroll
            for (int kk = 0; kk < 16; ++kk) {
                float4 av = *reinterpret_cast<const float4*>(&As[kk * 68 + tr * 4]);
                float4 bv = *reinterpret_cast<const float4*>(&Bs[kk * 64 + tc * 4]);
                float aa[4] = {av.x, av.y, av.z, av.w};
                float bb[4] = {bv.x, bv.y, bv.z, bv.w};
                #pragma unroll
                for (int i = 0; i < 4; ++i)
                    #pragma unroll
                    for (int j = 0; j < 4; ++j) acc[i][j] += aa[i] * bb[j];
            }
            __syncthreads();
        }
        #pragma unroll
        for (int i = 0; i < 4; ++i) {
            int row = r0 + tr * 4 + i;
            if (row < N_ATOMS) {
                half4_t hv;
                #pragma unroll
                for (int j = 0; j < 4; ++j) hv[j] = (half_t)acc[i][j];
                *reinterpret_cast<half4_t*>(&xbh[(size_t)row * 64 + tc * 4]) = hv;
            }
        }
    } else if (bid < XB_NB + SC_NB) {
        int i = (bid - XB_NB) * 256 + t;
        int s = ei[i];
        int d = ei[NEDGES + i];
        int k = tni[i];
        sidx[d * KMAX + k] = s;
    } else if (bid < XB_NB + SC_NB + WB_NB) {
        // Wb2[i]: e=i&7 | l=(i>>3)&63 | j=(i>>9)&15 | kh=(i>>13)&1 | ot=i>>14
        int i = (bid - XB_NB - SC_NB) * 256 + t;
        int e = i & 7, lv = (i >> 3) & 63;
        int c = lv & 15, g = lv >> 4;
        int kh = (i >> 13) & 1, ot = i >> 14;
        int o = ot * 16 + c;
        int idx = kh * 512 + ((i >> 9) & 15) * 32 + g * 8 + e;
        int r = ((idx >> 6) & 3) * 4 + (idx & 3);
        int p = (idx >> 8) * 16 + ((idx >> 2) & 15);
        Wb2[i] = (half_t)Wb[(size_t)(r * 64 + p) * 64 + o];
    } else if (bid < XB_NB + SC_NB + WB_NB + WU_NB) {
        // Wu2[i]: e=i&7 | l=(i>>3)&63 | kk=(i>>9)&1 | nt=(i>>10)&1 | w=i>>11
        int i = (bid - XB_NB - SC_NB - WB_NB) * 256 + t;
        int e = i & 7, lv = (i >> 3) & 63;
        int c = lv & 15, g = lv >> 4;
        int kk = (i >> 9) & 1, nt = (i >> 10) & 1, w = i >> 11;
        int oc = w * 32 + nt * 16 + c;
        int o = kk * 32 + g * 8 + e;
        Wu2[i] = (half_t)Wu[(size_t)o * 256 + oc];
    } else {
        if (t < 128) zrow[t] = (half_t)0.f;
    }
}

// ---------------------------------------------------------------------------
// consume one staged kc-batch (16 gathered rows) at LDS byte pointer stb
// ---------------------------------------------------------------------------
__device__ __forceinline__ void consume_batch(const char* stb, int c, int g,
                                              half4_t radf, half4_t ident,
                                              f32x4 (&acc)[4]) {
    const f32x4 fzero = {0.f, 0.f, 0.f, 0.f};
    #pragma unroll
    for (int pc = 0; pc < 4; ++pc) {
        int slot = (pc * 2 + (g >> 1)) ^ (c & 7);
        half4_t gf = *reinterpret_cast<const half4_t*>(
            stb + c * 128 + slot * 16 + (g & 1) * 8);
        // layout-convert A-frag -> B-frag via identity mfma (exact)
        f32x4 tD = __builtin_amdgcn_mfma_f32_16x16x16f16(gf, ident, fzero, 0, 0, 0);
        half4_t b2;
        #pragma unroll
        for (int j = 0; j < 4; ++j) b2[j] = (half_t)tD[j];
        acc[pc] = __builtin_amdgcn_mfma_f32_16x16x16f16(radf, b2, acc[pc], 0, 0, 0);
    }
}

// issue one kc-batch (2 x global_load_lds, 1 KB each) into Rbase+bufb
// sidx values come from the wave-resident sv register via shfl
#define ISSUE(as, kc, bufb) do {                                              \
    _Pragma("unroll")                                                         \
    for (int h_ = 0; h_ < 2; ++h_) {                                          \
        int s_ = __shfl(sv, (as) * 32 + (kc) * 16 + h_ * 8 + (l >> 3), 64);   \
        const half_t* src_ = ((unsigned)s_ < (unsigned)N_ATOMS)               \
            ? (xbh + (size_t)s_ * 64) : zrow;                                 \
        src_ += (((l & 7) ^ (l >> 3)) << 3);  /* swizzled 16B chunk */        \
        GLOAD_LDS16(src_, (half_t*)(Rbase + (bufb)) + h_ * 512);              \
    }                                                                         \
} while (0)

#define WRITE_ATOM(a_, accv) do {                                             \
    _Pragma("unroll")                                                         \
    for (int pc = 0; pc < 4; ++pc) {                                          \
        half4_t hv;                                                           \
        _Pragma("unroll")                                                     \
        for (int j = 0; j < 4; ++j) hv[j] = (half_t)accv[pc][j];              \
        int byte_ = ((a_) * 2048 + pc * 512 + g * 128 + c * 8) ^              \
                    (((a_) & 7) << 4);                                        \
        *reinterpret_cast<half4_t*>(reinterpret_cast<char*>(xba2s) + byte_) = hv; \
    }                                                                         \
} while (0)

#define WAIT_VM(n) do {                                                       \
    asm volatile("s_waitcnt vmcnt(" #n ")" ::: "memory");                     \
    __builtin_amdgcn_sched_barrier(0);                                        \
} while (0)

#define WAIT_LGKM() do {                                                      \
    asm volatile("s_waitcnt lgkmcnt(0)" ::: "memory");                        \
    __builtin_amdgcn_sched_barrier(0);                                        \
} while (0)

// ---------------------------------------------------------------------------
// Fused steps 3-5, MFMA f16. 16 atoms / block, 8 waves, 512 threads.
//  Stage buffers ALIAS the wave's own xba2s output region (43.5 KB LDS total
//  -> 3 blocks/CU). FIFO-ordered prologue: sidx(1), rad(4 linear), B0, B1,
//  Wb2(4); counted vmcnt(6/6/2/0) -> each wait exposes only incremental
//  latency. Atom-0 output write deferred until its buffer's staging is done.
// ---------------------------------------------------------------------------
__global__ __launch_bounds__(512, 6) void fused(const half_t* __restrict__ xbh,
                                                const float*  __restrict__ rad,   // (N,16,32) f32
                                                const int*    __restrict__ sidxg, // (N,32)
                                                const half_t* __restrict__ Wb2,   // (65536) permuted
                                                const half_t* __restrict__ Wu2,   // (16384) permuted
                                                const half_t* __restrict__ zrow,  // 128 zero f16
                                                float* __restrict__ out) {        // (N,256)
    __shared__ __align__(16) half_t xba2s[16 * 1024];  // 32 KB, outputs + stage (aliased)
    __shared__ __align__(16) float  preds[2 * 16 * 68]; // 8704 B split-K partials
    __shared__ __align__(16) half_t houts[16 * 64];     // 2048 B, row-swizzled

    const int t = threadIdx.x;
    const int w = t >> 6;        // wave 0..7
    const int l = t & 63;
    const int c = l & 15;
    const int g = l >> 4;
    const int a0 = blockIdx.x * 16;

    char* Rbase = reinterpret_cast<char*>(xba2s) + w * 4096;  // wave region: buf0 | buf1

    const f32x4 fzero = {0.f, 0.f, 0.f, 0.f};

    // ---- FIFO prologue: issue in consume order ----
    // op 1: sidx (64 ints = this wave's 2 atoms)
    int sv = sidxg[(size_t)(a0 + w * 2) * KMAX + l];
    // ops 2-5: rad, linear 1 KB loads (redistributed via shfl below)
    const float* radw = &rad[(size_t)(a0 + w * 2) * 512];
    f32x4 rv[4];
    #pragma unroll
    for (int q = 0; q < 4; ++q)
        rv[q] = *reinterpret_cast<const f32x4*>(radw + q * 256 + l * 4);

    // ops 6-9: gathers B0 (atom0 kc0 -> buf0), B1 (atom0 kc1 -> buf1)
    ISSUE(0, 0, 0);
    ISSUE(0, 1, 2048);
    __builtin_amdgcn_sched_barrier(0);

    // ops 10-13: Wb2 prefetch (phase 2 operands)
    const int ot = w >> 1, kh = w & 1;
    const half_t* wbbase = &Wb2[(size_t)((ot * 2 + kh) * 16) * 512];
    half8_t bfr[4];
    #pragma unroll
    for (int j = 0; j < 4; ++j)
        bfr[j] = *reinterpret_cast<const half8_t*>(wbbase + j * 512 + l * 8);
    __builtin_amdgcn_sched_barrier(0);

    // radF via shfl-BOTH-then-select (fix for round-5 bug: the half-select
    // must use the DESTINATION lane's row c>>3, so select after the shfl):
    //   radF[as][kc][j] = rad[as][r=c][k=kc*16+g*4+j]
    //   flat f = c*32+kc*16+g*4+j -> half = c>>3, srcl = (c&7)*8+kc*4+g, elem j
    half4_t radF[2][2];
    #pragma unroll
    for (int as = 0; as < 2; ++as)
        #pragma unroll
        for (int kc = 0; kc < 2; ++kc) {
            int srcl = (c & 7) * 8 + kc * 4 + g;
            #pragma unroll
            for (int j = 0; j < 4; ++j) {
                float lo = __shfl(rv[as * 2 + 0][j], srcl, 64);
                float hi = __shfl(rv[as * 2 + 1][j], srcl, 64);
                radF[as][kc][j] = (half_t)((c & 8) ? hi : lo);
            }
        }

    half4_t ident;  // identity B-frag: B[k][n] = (k==n)
    #pragma unroll
    for (int j = 0; j < 4; ++j) ident[j] = (half_t)((g * 4 + j == c) ? 1.0f : 0.0f);

    f32x4 acc0[4] = {fzero, fzero, fzero, fzero};
    f32x4 acc1[4] = {fzero, fzero, fzero, fzero};

    // ---- depth-2 consume chain, counted vmcnt ----
    WAIT_VM(6);                       // sidx+rad+B0 retired; B1+Wb2 in flight
    consume_batch(Rbase, c, g, radF[0][0], ident, acc0);
    WAIT_LGKM();
    ISSUE(1, 0, 0);                   // B2 -> buf0
    WAIT_VM(6);                       // B1 retired; Wb2+B2 in flight
    consume_batch(Rbase + 2048, c, g, radF[0][1], ident, acc0);
    WAIT_LGKM();
    ISSUE(1, 1, 2048);                // B3 -> buf1
    WAIT_VM(2);                       // Wb2+B2 retired; B3 in flight
    consume_batch(Rbase, c, g, radF[1][0], ident, acc1);
    WRITE_ATOM(w * 2, acc0);          // overwrite buf0 region (B2 consumed)
    WAIT_VM(0);                       // B3 retired
    consume_batch(Rbase + 2048, c, g, radF[1][1], ident, acc1);
    WRITE_ATOM(w * 2 + 1, acc1);      // overwrite buf1 region

    __syncthreads();

    // ---------------- phase 2: h_out(16x64) = xba2(16x1024) @ Wb ------------
    {
        f32x4 acc2[4] = {fzero, fzero, fzero, fzero};
        #pragma unroll
        for (int j = 0; j < 16; ++j) {
            int abyte = (c * 2048 + (kh * 512 + j * 32) * 2 + g * 16) ^ ((c & 7) << 4);
            half8_t af = *reinterpret_cast<const half8_t*>(
                reinterpret_cast<const char*>(xba2s) + abyte);
            half8_t bf = bfr[j & 3];
            if (j + 4 < 16)
                bfr[j & 3] = *reinterpret_cast<const half8_t*>(wbbase + (j + 4) * 512 + l * 8);
            acc2[j & 3] = __builtin_amdgcn_mfma_f32_16x16x32_f16(af, bf, acc2[j & 3], 0, 0, 0);
        }
        f32x4 accT = acc2[0] + acc2[1] + acc2[2] + acc2[3];
        #pragma unroll
        for (int i = 0; i < 4; ++i)
            preds[kh * 1088 + (g * 4 + i) * 68 + ot * 16 + c] = accT[i];
    }

    // prefetch all 4 Wu2 fragments across the barrier
    half8_t wuf[2][2];
    #pragma unroll
    for (int nt = 0; nt < 2; ++nt)
        #pragma unroll
        for (int kk = 0; kk < 2; ++kk)
            wuf[nt][kk] = *reinterpret_cast<const half8_t*>(
                &Wu2[(size_t)(((w * 2 + nt) * 2 + kk) * 64 + l) * 8]);

    __syncthreads();

    // reduce split-K partials -> houts f16 (row-swizzled)
    {
        int m = t >> 5, oj = (t & 31) << 1;
        float s0 = preds[m * 68 + oj]     + preds[1088 + m * 68 + oj];
        float s1 = preds[m * 68 + oj + 1] + preds[1088 + m * 68 + oj + 1];
        half2_t hv; hv[0] = (half_t)s0; hv[1] = (half_t)s1;
        int byte_ = (m * 128 + oj * 2) ^ ((m & 7) << 4);
        *reinterpret_cast<half2_t*>(reinterpret_cast<char*>(houts) + byte_) = hv;
    }
    __syncthreads();

    // ---------------- phase 3: out(16x256) = hout(16x64) @ Wu ---------------
    half8_t ha[2];
    #pragma unroll
    for (int kk = 0; kk < 2; ++kk) {
        int byte_ = (c * 128 + kk * 64 + g * 16) ^ ((c & 7) << 4);
        ha[kk] = *reinterpret_cast<const half8_t*>(
            reinterpret_cast<const char*>(houts) + byte_);
    }
    #pragma unroll
    for (int nt = 0; nt < 2; ++nt) {
        int oc0 = w * 32 + nt * 16;
        f32x4 acc3 = fzero;
        #pragma unroll
        for (int kk = 0; kk < 2; ++kk)
            acc3 = __builtin_amdgcn_mfma_f32_16x16x32_f16(ha[kk], wuf[nt][kk], acc3, 0, 0, 0);
        #pragma unroll
        for (int i = 0; i < 4; ++i)
            out[(size_t)(a0 + g * 4 + i) * 256 + oc0 + c] = acc3[i];
    }
}

// ---------------------------------------------------------------------------
extern "C" void kernel_launch(void* const* d_in, const int* in_sizes, int n_in,
                              void* d_out, int out_size, void* d_ws, size_t ws_size,
                              hipStream_t stream) {
    const float* h   = (const float*)d_in[0];
    const float* rad = (const float*)d_in[1];
    const int*   ei  = (const int*)d_in[2];
    const int*   tni = (const int*)d_in[3];
    const float* Wd  = (const float*)d_in[4];
    const float* Wb  = (const float*)d_in[5];
    const float* Wu  = (const float*)d_in[6];
    float* out = (float*)d_out;

    // workspace: xbh f16 6.4MB | sidx i32 6.4MB | Wb2 128KB | Wu2 32KB | zrow 256B
    half_t* xbh  = (half_t*)d_ws;
    int*    sidx = (int*)((char*)d_ws + (size_t)N_ATOMS * EP_IN * sizeof(half_t));
    half_t* Wb2  = (half_t*)((char*)sidx + (size_t)NEDGES * sizeof(int));
    half_t* Wu2  = Wb2 + 64 * 1024;
    half_t* zrow = Wu2 + 16384;

    prep_all<<<PREP_NB, 256, 0, stream>>>(h, Wd, ei, tni, Wb, Wu,
                                          xbh, sidx, Wb2, Wu2, zrow);
    fused<<<N_ATOMS / 16, 512, 0, stream>>>(xbh, rad, sidx, Wb2, Wu2, zrow, out);
}